// Round 10
// baseline (158.695 us; speedup 1.0000x reference)
//
#include <hip/hip_runtime.h>
#include <hip/hip_fp16.h>
#include <math.h>

#define IN_F 64
#define OUT_F 32
#define NEG_SLOPE 0.2f

#define BK_SHIFT 6
#define BK 64            // nodes per bucket (was 128; halved for k_pg occupancy)
#define NBMAX 2048       // max buckets (N <= 131072)
#define NBLKA 256        // edge-pass block count (= per-bucket scan width)
#define PSTAGE 3         // k_pg register staging (512 thr x 3 = 1536 >= ~1024+6sigma)
#define COLCAP 2048      // LDS col capacity per bucket (mean ~1023 + pad<=192)

typedef _Float16 half8_t __attribute__((ext_vector_type(8)));
typedef float float4_t __attribute__((ext_vector_type(4)));
typedef int int4_t __attribute__((ext_vector_type(4)));

// SESSION FINDINGS:
//  - gfx950 LDS atomics ~4.2 cy per LANE-op, unpipelined RMW. Budget 1-2 per
//    edge (33/edge = 355us wall, rounds 2-7).
//  - k_gather mixed VALU/VMEM: pad16 traffic cancelled clamp removal (r8);
//    pad4 keeps both.
//  - place+gather fusion: -20us (r9). k_pg then latency-bound at 42% occupancy
//    (3.05 blocks/CU quantization) -> BK 64 + boff precompute (this round).

__device__ __forceinline__ float leaky(float v) {
    return (v > 0.0f) ? v : NEG_SLOPE * v;
}

// Inclusive block scan, 256 threads. wsum: >=4-int LDS scratch.
__device__ __forceinline__ int incScan256(int v, int tid, int* wsum) {
    const int lane = tid & 63, wid = tid >> 6;
    #pragma unroll
    for (int m = 1; m < 64; m <<= 1) {
        int u = __shfl_up(v, m);
        if (lane >= m) v += u;
    }
    if (lane == 63) wsum[wid] = v;
    __syncthreads();
    int add = 0;
    for (int k = 0; k < wid; ++k) add += wsum[k];
    __syncthreads();
    return v + add;
}

// Inclusive block scan, 512 threads. wsum: >=8-int LDS scratch.
__device__ __forceinline__ int incScan512(int v, int tid, int* wsum) {
    const int lane = tid & 63, wid = tid >> 6;
    #pragma unroll
    for (int m = 1; m < 64; m <<= 1) {
        int u = __shfl_up(v, m);
        if (lane >= m) v += u;
    }
    if (lane == 63) wsum[wid] = v;
    __syncthreads();
    int add = 0;
    for (int k = 0; k < wid; ++k) add += wsum[k];
    __syncthreads();
    return v + add;
}

// Fused: blocks [0, PB) MFMA projection (16 nodes/wave, 64/block, no LDS);
// blocks [PB, PB+NBLKA) coarse histogram (LDS).
__global__ __launch_bounds__(256) void k_projhist(
        const float* __restrict__ x, const float* __restrict__ W,
        const float* __restrict__ att_src, const float* __restrict__ att_dst,
        __half2* __restrict__ h2, float* __restrict__ asrc, float* __restrict__ adst,
        const int* __restrict__ dst, int* __restrict__ hist,
        int N, int NB, int E, int epb, int PB) {
    __shared__ int smem[2560];               // 10 KB (hist role only; NB<=2048)
    const int tid = threadIdx.x;

    if (blockIdx.x >= PB) {
        // ---- coarse histogram role: hist[b*NBLKA + blk] ----
        int* lh = smem;
        const int blk = blockIdx.x - PB;
        for (int i = tid; i < NB; i += 256) lh[i] = 0;
        __syncthreads();
        const int e0 = blk * epb, e1 = min(E, e0 + epb);
        for (int e = e0 + tid; e < e1; e += 256) atomicAdd(&lh[dst[e] >> BK_SHIFT], 1);
        __syncthreads();
        for (int b = tid; b < NB; b += 256) hist[(size_t)b * NBLKA + blk] = lh[b];
        return;
    }

    // ---- MFMA projection role ----
    const int wv   = tid >> 6;               // wave 0..3
    const int lane = tid & 63;
    const int m    = lane & 15;              // node-in-16 (A) / channel-in-group (B, C/D)
    const int quad = lane >> 4;              // 0..3
    const int node0 = (blockIdx.x * 4 + wv) * 16;
    if (node0 >= N) return;

    const int kb = quad * 8;
    // B fragments (W is 64x32, row-major W[k*32+c]); built once, L2-hot.
    half8_t b00, b01, b10, b11;
    #pragma unroll
    for (int j = 0; j < 8; ++j) {
        b00[j] = (_Float16)W[(kb + j) * OUT_F + m];
        b01[j] = (_Float16)W[(32 + kb + j) * OUT_F + m];
        b10[j] = (_Float16)W[(kb + j) * OUT_F + 16 + m];
        b11[j] = (_Float16)W[(32 + kb + j) * OUT_F + 16 + m];
    }
    // A fragments: x row (clamped in the tail block), 2x float4 per K-chunk.
    const int row = min(node0 + m, N - 1);
    const float* xr = x + (size_t)row * IN_F + kb;
    float4_t xa = *(const float4_t*)(xr);
    float4_t xb = *(const float4_t*)(xr + 4);
    float4_t xc = *(const float4_t*)(xr + 32);
    float4_t xd = *(const float4_t*)(xr + 36);
    half8_t a0, a1;
    #pragma unroll
    for (int j = 0; j < 4; ++j) {
        a0[j] = (_Float16)xa[j]; a0[4 + j] = (_Float16)xb[j];
        a1[j] = (_Float16)xc[j]; a1[4 + j] = (_Float16)xd[j];
    }
    float4_t acc0 = {0.f, 0.f, 0.f, 0.f};
    float4_t acc1 = {0.f, 0.f, 0.f, 0.f};
    acc0 = __builtin_amdgcn_mfma_f32_16x16x32_f16(a0, b00, acc0, 0, 0, 0);
    acc0 = __builtin_amdgcn_mfma_f32_16x16x32_f16(a1, b01, acc0, 0, 0, 0);
    acc1 = __builtin_amdgcn_mfma_f32_16x16x32_f16(a0, b10, acc1, 0, 0, 0);
    acc1 = __builtin_amdgcn_mfma_f32_16x16x32_f16(a1, b11, acc1, 0, 0, 0);

    // Epilogue: h2 (fp16 pairs) + asrc/adst per node.
    const float aS0 = att_src[m], aS1 = att_src[16 + m];
    const float aD0 = att_dst[m], aD1 = att_dst[16 + m];
    #pragma unroll
    for (int r = 0; r < 4; ++r) {
        const int node = node0 + quad * 4 + r;
        float h0 = acc0[r], h1 = acc1[r];
        float h0p = __shfl_xor(h0, 1);
        float h1p = __shfl_xor(h1, 1);
        if (node < N && (m & 1) == 0) {
            __half2 hv;
            hv.x = __float2half_rn(h0); hv.y = __float2half_rn(h0p);
            h2[(size_t)node * 16 + (m >> 1)] = hv;
            __half2 hw;
            hw.x = __float2half_rn(h1); hw.y = __float2half_rn(h1p);
            h2[(size_t)node * 16 + 8 + (m >> 1)] = hw;
        }
        float vs = h0 * aS0 + h1 * aS1;
        float vd = h0 * aD0 + h1 * aD1;
        #pragma unroll
        for (int mm = 1; mm < 16; mm <<= 1) {
            vs += __shfl_xor(vs, mm);
            vd += __shfl_xor(vd, mm);
        }
        if (node < N && m == 0) {
            asrc[node] = vs;
            adst[node] = vd;
        }
    }
}

// Scan 1: one block per bucket; exclusive scan of hist[b][0..NBLKA) in place,
// bucket total -> bsum[b]. Block 0 also initializes the gather sentinel:
// h2 row N = 0, asrc[N] = -1e30 (=> p = exp(-2e29) = 0 exactly).
__global__ __launch_bounds__(256) void k_scan1(int* __restrict__ hist,
                                               int* __restrict__ bsum,
                                               __half2* __restrict__ h2,
                                               float* __restrict__ asrc,
                                               int N, int NB) {
    __shared__ int wsum[4];
    const int b = blockIdx.x, tid = threadIdx.x;
    if (b == 0) {
        if (tid < 16) h2[(size_t)N * 16 + tid] = __floats2half2_rn(0.0f, 0.0f);
        if (tid == 16) asrc[N] = -1e30f;
    }
    int v = hist[(size_t)b * NBLKA + tid];
    const int inc = incScan256(v, tid, wsum);
    hist[(size_t)b * NBLKA + tid] = inc - v;
    if (tid == 255) bsum[b] = inc;
}

// Pass B: 512 threads/block. 4-way local scan of bucket totals -> tt (exclusive
// bases); block 0 publishes boff[0..NB] (so k_pg needs no scan); seed cursors;
// place packed records (d&63)<<17 | s into private runs.
__global__ __launch_bounds__(512) void k_bpart(const int* __restrict__ src,
                                               const int* __restrict__ dst,
                                               const int* __restrict__ hist,
                                               const int* __restrict__ bsum,
                                               int* __restrict__ recs,
                                               int* __restrict__ boff,
                                               int NB, int E, int epb) {
    __shared__ int tt[NBMAX];
    __shared__ int lcur[NBMAX];
    __shared__ int wsum[8];
    const int tid = threadIdx.x, blk = blockIdx.x;
    for (int i = tid; i < NBMAX; i += 512) tt[i] = (i < NB) ? bsum[i] : 0;
    __syncthreads();
    {
        int a0 = tt[tid * 4], a1 = tt[tid * 4 + 1], a2 = tt[tid * 4 + 2], a3 = tt[tid * 4 + 3];
        int s = a0 + a1 + a2 + a3;
        int inc = incScan512(s, tid, wsum);
        int run = inc - s;
        tt[tid * 4] = run;     run += a0;
        tt[tid * 4 + 1] = run; run += a1;
        tt[tid * 4 + 2] = run; run += a2;
        tt[tid * 4 + 3] = run;
    }
    __syncthreads();
    if (blk == 0) {
        for (int b = tid; b < NB; b += 512) boff[b] = tt[b];
        if (tid == 0) boff[NB] = E;
    }
    for (int b = tid; b < NB; b += 512)
        lcur[b] = hist[(size_t)b * NBLKA + blk] + tt[b];
    __syncthreads();
    const int e0 = blk * epb, e1 = min(E, e0 + epb);
    for (int e = e0 + tid; e < e1; e += 512) {
        int s = src[e];
        int d = dst[e];
        int p = atomicAdd(&lcur[d >> BK_SHIFT], 1);   // LDS cursor, block-private
        recs[p] = ((d & (BK - 1)) << 17) | s;
    }
}

// Fused place+gather: one block per bucket (64 nodes, 512 threads = 8 waves).
// Prologue: cb0/cb1 from boff (no scan). Phase 1 (place): fine histogram of
// recs; padded (x4) scan; place col into sentinel-prefilled LDS. Phase 2
// (gather): wave w handles nodes w*8..w*8+7; 4x16-lane groups read chunk
// lists from LDS (ds_read_b128) and gather h2/asrc from global.
__global__ __launch_bounds__(512) void k_pg(const int* __restrict__ recs,
                                            const int* __restrict__ boff,
                                            const float* __restrict__ asrc,
                                            const float* __restrict__ adst,
                                            const __half2* __restrict__ h2,
                                            const float* __restrict__ bias,
                                            float* __restrict__ out,
                                            int NB, int E, int N) {
    __shared__ __align__(16) int colsh[COLCAP];
    __shared__ int fineCnt[BK];
    __shared__ int cur[BK];
    __shared__ int loff[BK];
    __shared__ int lpad[BK];
    __shared__ int wsum[8];
    const int b = blockIdx.x, tid = threadIdx.x;
    const int node0 = b << BK_SHIFT;

    const int cb0 = boff[b];
    const int cb1 = boff[b + 1];
    const int count = cb1 - cb0;

    // ---- init: sentinel prefill + zero counts ----
    for (int i = tid; i < COLCAP; i += 512) colsh[i] = N;
    if (tid < BK) fineCnt[tid] = 0;
    __syncthreads();

    // ---- fine histogram (register-staged) ----
    int myrec[PSTAGE];
    #pragma unroll
    for (int k = 0; k < PSTAGE; ++k) {
        int i = tid + k * 512;
        if (i < count) {
            int v = recs[cb0 + i];
            myrec[k] = v;
            atomicAdd(&fineCnt[v >> 17], 1);
        }
    }
    for (int i = tid + PSTAGE * 512; i < count; i += 512)   // statistically never
        atomicAdd(&fineCnt[recs[cb0 + i] >> 17], 1);
    __syncthreads();

    // ---- padded (x4) scan of per-node counts ----
    const int v0 = (tid < BK) ? fineCnt[tid] : 0;
    const int pv = (v0 + 3) & ~3;
    const int vin = (tid < BK) ? pv : 0;
    const int pinc = incScan512(vin, tid, wsum);
    const int pexcl = pinc - vin;
    if (tid < BK) {
        loff[tid] = pexcl;       // multiple of 4 -> 16B-aligned chunks
        lpad[tid] = pv;
        cur[tid]  = pexcl;
    }
    __syncthreads();

    // ---- place into LDS col ----
    #pragma unroll
    for (int k = 0; k < PSTAGE; ++k) {
        int i = tid + k * 512;
        if (i < count) {
            int r = myrec[k];
            int p = atomicAdd(&cur[r >> 17], 1);
            colsh[p] = r & 0x1FFFF;
        }
    }
    for (int i = tid + PSTAGE * 512; i < count; i += 512) {
        int r = recs[cb0 + i];
        int p = atomicAdd(&cur[r >> 17], 1);
        colsh[p] = r & 0x1FFFF;
    }
    __syncthreads();

    // ---- gather: wave w -> nodes node0 + w*8 .. +7 ----
    const int wid  = tid >> 6;
    const int lane = tid & 63;
    const int g    = lane >> 4;      // edge group 0..3
    const int c2   = lane & 15;      // half2 channel pair
    for (int i = 0; i < 8; ++i) {
        const int dloc = wid * 8 + i;
        const int n = node0 + dloc;
        if (n >= N) break;           // only the tail bucket; uniform per wave
        const float adst_n = adst[n];
        float l = 0.0f, accx = 0.0f, accy = 0.0f;
        if (g == 0) {                // self loop
            float p = __expf(leaky(asrc[n] + adst_n));
            float2 hv = __half22float2(h2[(size_t)n * 16 + c2]);
            l = p; accx = p * hv.x; accy = p * hv.y;
        }
        const int base = loff[dloc];
        const int nch  = lpad[dloc] >> 2;    // 4-edge chunks
        for (int c = g; c < nch; c += 4) {   // clamp-free (sentinel-padded x4)
            const int4_t cc = *(const int4_t*)(&colsh[base + c * 4]);
            const int s0 = cc[0], s1 = cc[1], s2 = cc[2], s3 = cc[3];
            float a0 = asrc[s0], a1 = asrc[s1], a2 = asrc[s2], a3 = asrc[s3];
            float2 h0 = __half22float2(h2[(size_t)s0 * 16 + c2]);
            float2 h1 = __half22float2(h2[(size_t)s1 * 16 + c2]);
            float2 hv2 = __half22float2(h2[(size_t)s2 * 16 + c2]);
            float2 h3 = __half22float2(h2[(size_t)s3 * 16 + c2]);
            float p0 = __expf(leaky(a0 + adst_n));
            float p1 = __expf(leaky(a1 + adst_n));
            float p2 = __expf(leaky(a2 + adst_n));
            float p3 = __expf(leaky(a3 + adst_n));
            l += (p0 + p1) + (p2 + p3);
            accx += p0 * h0.x + p1 * h1.x + p2 * hv2.x + p3 * h3.x;
            accy += p0 * h0.y + p1 * h1.y + p2 * hv2.y + p3 * h3.y;
        }
        l    += __shfl_xor(l, 16);    l    += __shfl_xor(l, 32);
        accx += __shfl_xor(accx, 16); accx += __shfl_xor(accx, 32);
        accy += __shfl_xor(accy, 16); accy += __shfl_xor(accy, 32);
        if (g == 0) {
            float inv = 1.0f / l;
            float2 bb = ((const float2*)bias)[c2];
            float2 o;
            o.x = fmaxf(accx * inv + bb.x, 0.0f);
            o.y = fmaxf(accy * inv + bb.y, 0.0f);
            ((float2*)out)[(size_t)n * 16 + c2] = o;
        }
    }
}

extern "C" void kernel_launch(void* const* d_in, const int* in_sizes, int n_in,
                              void* d_out, int out_size, void* d_ws, size_t ws_size,
                              hipStream_t stream) {
    const float* x        = (const float*)d_in[0];
    const int*   eidx     = (const int*)d_in[1];   // [2, E] flat int32
    const float* W        = (const float*)d_in[2];
    const float* att_src  = (const float*)d_in[3];
    const float* att_dst  = (const float*)d_in[4];
    const float* bias     = (const float*)d_in[5];
    float* out = (float*)d_out;

    const int N = in_sizes[0] / IN_F;
    const int E = in_sizes[1] / 2;
    const int* src = eidx;
    const int* dst = eidx + E;

    const int NB  = (N + BK - 1) >> BK_SHIFT;    // 1563 buckets
    const int epb = (E + NBLKA - 1) / NBLKA;     // edges per hist/bpart block

    // Workspace (4 B elems, ~16 MB)
    int* u = (int*)d_ws;
    size_t o = 0;
    __half2* h2   = (__half2*)(u + o); o += (size_t)(N + 1) * 16;   // +sentinel row
    float*   asrc = (float*)(u + o);   o += N + 1;                  // +sentinel
    float*   adst = (float*)(u + o);   o += N;
    int*     hist = u + o;             o += (size_t)NB * NBLKA;     // ~400k
    int*     bsum = u + o;             o += NBMAX;
    int*     boff = u + o;             o += NBMAX + 1;
    int*     recs = u + o;             o += E;

    const int PB = (N + 63) / 64;                // MFMA proj blocks (64 nodes/block)

    k_projhist<<<PB + NBLKA, 256, 0, stream>>>(x, W, att_src, att_dst, h2, asrc, adst,
                                               dst, hist, N, NB, E, epb, PB);
    k_scan1<<<NB, 256, 0, stream>>>(hist, bsum, h2, asrc, N, NB);
    k_bpart<<<NBLKA, 512, 0, stream>>>(src, dst, hist, bsum, recs, boff, NB, E, epb);
    k_pg<<<NB, 512, 0, stream>>>(recs, boff, asrc, adst, h2, bias, out, NB, E, N);
}

// Round 11
// 153.568 us; speedup vs baseline: 1.0334x; 1.0334x over previous
//
#include <hip/hip_runtime.h>
#include <hip/hip_fp16.h>
#include <math.h>

#define IN_F 64
#define OUT_F 32
#define NEG_SLOPE 0.2f

#define BK_SHIFT 6
#define BK 64            // nodes per bucket
#define NBMAX 2048       // max buckets (N <= 131072)
#define NBLKA 256        // bpart block count
#define PSTAGE 3         // k_pg register staging (512 thr x 3 = 1536 >= ~1024+6sigma)
#define CAPSHIFT 11
#define CAP 2048         // fixed recs capacity per bucket (mean 1024, sd 32 -> 32 sigma)
#define COLCAP 2048      // LDS col capacity per bucket

typedef _Float16 half8_t __attribute__((ext_vector_type(8)));
typedef float float4_t __attribute__((ext_vector_type(4)));
typedef int int4_t __attribute__((ext_vector_type(4)));

// SESSION FINDINGS:
//  - gfx950 LDS atomics ~4.2 cy per LANE-op, unpipelined RMW. Budget 1-2/edge.
//  - k_pg at its DS+VMEM overlap floor (~46us); occupancy 42->54% bought only 2.5us.
//  - r11: upstream CSR-prep was 107us (2/3 of total). Exact contiguous bucket
//    bases (hist edge-pass + scan1 + boff) replaced by fixed-CAP regions +
//    one global atomicAdd chunk reservation per (block,bucket).

__device__ __forceinline__ float leaky(float v) {
    return (v > 0.0f) ? v : NEG_SLOPE * v;
}

// Inclusive block scan, 512 threads. wsum: >=8-int LDS scratch.
__device__ __forceinline__ int incScan512(int v, int tid, int* wsum) {
    const int lane = tid & 63, wid = tid >> 6;
    #pragma unroll
    for (int m = 1; m < 64; m <<= 1) {
        int u = __shfl_up(v, m);
        if (lane >= m) v += u;
    }
    if (lane == 63) wsum[wid] = v;
    __syncthreads();
    int add = 0;
    for (int k = 0; k < wid; ++k) add += wsum[k];
    __syncthreads();
    return v + add;
}

// Blocks [0, PB): MFMA projection (16 nodes/wave, 64/block, no LDS).
// Block PB: init bucket cursors (cursor[b] = b*CAP) + gather sentinel
// (h2 row N = 0, asrc[N] = -1e30 => p = 0).
__global__ __launch_bounds__(256) void k_proj(
        const float* __restrict__ x, const float* __restrict__ W,
        const float* __restrict__ att_src, const float* __restrict__ att_dst,
        __half2* __restrict__ h2, float* __restrict__ asrc, float* __restrict__ adst,
        int* __restrict__ cursor, int N, int NB, int PB) {
    const int tid = threadIdx.x;

    if (blockIdx.x >= PB) {
        // ---- init role ----
        for (int b = tid; b < NB; b += 256) cursor[b] = b << CAPSHIFT;
        if (tid < 16) h2[(size_t)N * 16 + tid] = __floats2half2_rn(0.0f, 0.0f);
        if (tid == 16) asrc[N] = -1e30f;
        return;
    }

    // ---- MFMA projection role ----
    const int wv   = tid >> 6;               // wave 0..3
    const int lane = tid & 63;
    const int m    = lane & 15;              // node-in-16 (A) / channel-in-group (B, C/D)
    const int quad = lane >> 4;              // 0..3
    const int node0 = (blockIdx.x * 4 + wv) * 16;
    if (node0 >= N) return;

    const int kb = quad * 8;
    // B fragments (W is 64x32, row-major W[k*32+c]); built once, L2-hot.
    half8_t b00, b01, b10, b11;
    #pragma unroll
    for (int j = 0; j < 8; ++j) {
        b00[j] = (_Float16)W[(kb + j) * OUT_F + m];
        b01[j] = (_Float16)W[(32 + kb + j) * OUT_F + m];
        b10[j] = (_Float16)W[(kb + j) * OUT_F + 16 + m];
        b11[j] = (_Float16)W[(32 + kb + j) * OUT_F + 16 + m];
    }
    // A fragments: x row (clamped in the tail block), 2x float4 per K-chunk.
    const int row = min(node0 + m, N - 1);
    const float* xr = x + (size_t)row * IN_F + kb;
    float4_t xa = *(const float4_t*)(xr);
    float4_t xb = *(const float4_t*)(xr + 4);
    float4_t xc = *(const float4_t*)(xr + 32);
    float4_t xd = *(const float4_t*)(xr + 36);
    half8_t a0, a1;
    #pragma unroll
    for (int j = 0; j < 4; ++j) {
        a0[j] = (_Float16)xa[j]; a0[4 + j] = (_Float16)xb[j];
        a1[j] = (_Float16)xc[j]; a1[4 + j] = (_Float16)xd[j];
    }
    float4_t acc0 = {0.f, 0.f, 0.f, 0.f};
    float4_t acc1 = {0.f, 0.f, 0.f, 0.f};
    acc0 = __builtin_amdgcn_mfma_f32_16x16x32_f16(a0, b00, acc0, 0, 0, 0);
    acc0 = __builtin_amdgcn_mfma_f32_16x16x32_f16(a1, b01, acc0, 0, 0, 0);
    acc1 = __builtin_amdgcn_mfma_f32_16x16x32_f16(a0, b10, acc1, 0, 0, 0);
    acc1 = __builtin_amdgcn_mfma_f32_16x16x32_f16(a1, b11, acc1, 0, 0, 0);

    // Epilogue: h2 (fp16 pairs) + asrc/adst per node.
    const float aS0 = att_src[m], aS1 = att_src[16 + m];
    const float aD0 = att_dst[m], aD1 = att_dst[16 + m];
    #pragma unroll
    for (int r = 0; r < 4; ++r) {
        const int node = node0 + quad * 4 + r;
        float h0 = acc0[r], h1 = acc1[r];
        float h0p = __shfl_xor(h0, 1);
        float h1p = __shfl_xor(h1, 1);
        if (node < N && (m & 1) == 0) {
            __half2 hv;
            hv.x = __float2half_rn(h0); hv.y = __float2half_rn(h0p);
            h2[(size_t)node * 16 + (m >> 1)] = hv;
            __half2 hw;
            hw.x = __float2half_rn(h1); hw.y = __float2half_rn(h1p);
            h2[(size_t)node * 16 + 8 + (m >> 1)] = hw;
        }
        float vs = h0 * aS0 + h1 * aS1;
        float vd = h0 * aD0 + h1 * aD1;
        #pragma unroll
        for (int mm = 1; mm < 16; mm <<= 1) {
            vs += __shfl_xor(vs, mm);
            vd += __shfl_xor(vd, mm);
        }
        if (node < N && m == 0) {
            asrc[node] = vs;
            adst[node] = vd;
        }
    }
}

// Bucket partition, fixed-CAP chunk reservation (no hist, no scan, no boff):
// pass A: LDS-count this block's edges per bucket; reserve a contiguous chunk
// per non-empty bucket via ONE global atomicAdd(cursor[b], cnt); pass B:
// re-read edges, place packed records (d&63)<<17 | s via LDS cursor.
__global__ __launch_bounds__(512) void k_bpart(const int* __restrict__ src,
                                               const int* __restrict__ dst,
                                               int* __restrict__ cursor,
                                               int* __restrict__ recs,
                                               int NB, int E, int epb) {
    __shared__ int cnt[NBMAX];
    __shared__ int lcur[NBMAX];
    const int tid = threadIdx.x, blk = blockIdx.x;
    for (int b = tid; b < NB; b += 512) cnt[b] = 0;
    __syncthreads();
    const int e0 = blk * epb, e1 = min(E, e0 + epb);
    for (int e = e0 + tid; e < e1; e += 512)
        atomicAdd(&cnt[dst[e] >> BK_SHIFT], 1);
    __syncthreads();
    for (int b = tid; b < NB; b += 512) {
        const int c = cnt[b];
        if (c > 0) lcur[b] = atomicAdd(&cursor[b], c);   // global chunk reserve
    }
    __syncthreads();
    for (int e = e0 + tid; e < e1; e += 512) {
        int s = src[e];
        int d = dst[e];
        int p = atomicAdd(&lcur[d >> BK_SHIFT], 1);      // LDS cursor
        recs[p] = ((d & (BK - 1)) << 17) | s;
    }
}

// Fused place+gather: one block per bucket (64 nodes, 512 threads = 8 waves).
// cb0 = b*CAP; count = cursor[b] - cb0. Phase 1 (place): fine histogram of
// recs; padded (x4) scan; place col into sentinel-prefilled LDS. Phase 2
// (gather): wave w handles nodes w*8..w*8+7; 4x16-lane groups read chunk
// lists from LDS (ds_read_b128) and gather h2/asrc from global.
__global__ __launch_bounds__(512) void k_pg(const int* __restrict__ recs,
                                            const int* __restrict__ cursor,
                                            const float* __restrict__ asrc,
                                            const float* __restrict__ adst,
                                            const __half2* __restrict__ h2,
                                            const float* __restrict__ bias,
                                            float* __restrict__ out,
                                            int NB, int E, int N) {
    __shared__ __align__(16) int colsh[COLCAP];
    __shared__ int fineCnt[BK];
    __shared__ int cur[BK];
    __shared__ int loff[BK];
    __shared__ int lpad[BK];
    __shared__ int wsum[8];
    const int b = blockIdx.x, tid = threadIdx.x;
    const int node0 = b << BK_SHIFT;

    const int cb0 = b << CAPSHIFT;
    const int count = min(cursor[b] - cb0, CAP);

    // ---- init: sentinel prefill + zero counts ----
    for (int i = tid; i < COLCAP; i += 512) colsh[i] = N;
    if (tid < BK) fineCnt[tid] = 0;
    __syncthreads();

    // ---- fine histogram (register-staged) ----
    int myrec[PSTAGE];
    #pragma unroll
    for (int k = 0; k < PSTAGE; ++k) {
        int i = tid + k * 512;
        if (i < count) {
            int v = recs[cb0 + i];
            myrec[k] = v;
            atomicAdd(&fineCnt[v >> 17], 1);
        }
    }
    for (int i = tid + PSTAGE * 512; i < count; i += 512)   // statistically never
        atomicAdd(&fineCnt[recs[cb0 + i] >> 17], 1);
    __syncthreads();

    // ---- padded (x4) scan of per-node counts ----
    const int v0 = (tid < BK) ? fineCnt[tid] : 0;
    const int pv = (v0 + 3) & ~3;
    const int vin = (tid < BK) ? pv : 0;
    const int pinc = incScan512(vin, tid, wsum);
    const int pexcl = pinc - vin;
    if (tid < BK) {
        loff[tid] = pexcl;       // multiple of 4 -> 16B-aligned chunks
        lpad[tid] = pv;
        cur[tid]  = pexcl;
    }
    __syncthreads();

    // ---- place into LDS col ----
    #pragma unroll
    for (int k = 0; k < PSTAGE; ++k) {
        int i = tid + k * 512;
        if (i < count) {
            int r = myrec[k];
            int p = atomicAdd(&cur[r >> 17], 1);
            colsh[p] = r & 0x1FFFF;
        }
    }
    for (int i = tid + PSTAGE * 512; i < count; i += 512) {
        int r = recs[cb0 + i];
        int p = atomicAdd(&cur[r >> 17], 1);
        colsh[p] = r & 0x1FFFF;
    }
    __syncthreads();

    // ---- gather: wave w -> nodes node0 + w*8 .. +7 ----
    const int wid  = tid >> 6;
    const int lane = tid & 63;
    const int g    = lane >> 4;      // edge group 0..3
    const int c2   = lane & 15;      // half2 channel pair
    for (int i = 0; i < 8; ++i) {
        const int dloc = wid * 8 + i;
        const int n = node0 + dloc;
        if (n >= N) break;           // only the tail bucket; uniform per wave
        const float adst_n = adst[n];
        float l = 0.0f, accx = 0.0f, accy = 0.0f;
        if (g == 0) {                // self loop
            float p = __expf(leaky(asrc[n] + adst_n));
            float2 hv = __half22float2(h2[(size_t)n * 16 + c2]);
            l = p; accx = p * hv.x; accy = p * hv.y;
        }
        const int base = loff[dloc];
        const int nch  = lpad[dloc] >> 2;    // 4-edge chunks
        for (int c = g; c < nch; c += 4) {   // clamp-free (sentinel-padded x4)
            const int4_t cc = *(const int4_t*)(&colsh[base + c * 4]);
            const int s0 = cc[0], s1 = cc[1], s2 = cc[2], s3 = cc[3];
            float a0 = asrc[s0], a1 = asrc[s1], a2 = asrc[s2], a3 = asrc[s3];
            float2 h0 = __half22float2(h2[(size_t)s0 * 16 + c2]);
            float2 h1 = __half22float2(h2[(size_t)s1 * 16 + c2]);
            float2 hv2 = __half22float2(h2[(size_t)s2 * 16 + c2]);
            float2 h3 = __half22float2(h2[(size_t)s3 * 16 + c2]);
            float p0 = __expf(leaky(a0 + adst_n));
            float p1 = __expf(leaky(a1 + adst_n));
            float p2 = __expf(leaky(a2 + adst_n));
            float p3 = __expf(leaky(a3 + adst_n));
            l += (p0 + p1) + (p2 + p3);
            accx += p0 * h0.x + p1 * h1.x + p2 * hv2.x + p3 * h3.x;
            accy += p0 * h0.y + p1 * h1.y + p2 * hv2.y + p3 * h3.y;
        }
        l    += __shfl_xor(l, 16);    l    += __shfl_xor(l, 32);
        accx += __shfl_xor(accx, 16); accx += __shfl_xor(accx, 32);
        accy += __shfl_xor(accy, 16); accy += __shfl_xor(accy, 32);
        if (g == 0) {
            float inv = 1.0f / l;
            float2 bb = ((const float2*)bias)[c2];
            float2 o;
            o.x = fmaxf(accx * inv + bb.x, 0.0f);
            o.y = fmaxf(accy * inv + bb.y, 0.0f);
            ((float2*)out)[(size_t)n * 16 + c2] = o;
        }
    }
}

extern "C" void kernel_launch(void* const* d_in, const int* in_sizes, int n_in,
                              void* d_out, int out_size, void* d_ws, size_t ws_size,
                              hipStream_t stream) {
    const float* x        = (const float*)d_in[0];
    const int*   eidx     = (const int*)d_in[1];   // [2, E] flat int32
    const float* W        = (const float*)d_in[2];
    const float* att_src  = (const float*)d_in[3];
    const float* att_dst  = (const float*)d_in[4];
    const float* bias     = (const float*)d_in[5];
    float* out = (float*)d_out;

    const int N = in_sizes[0] / IN_F;
    const int E = in_sizes[1] / 2;
    const int* src = eidx;
    const int* dst = eidx + E;

    const int NB  = (N + BK - 1) >> BK_SHIFT;    // 1563 buckets
    const int epb = (E + NBLKA - 1) / NBLKA;     // edges per bpart block

    // Workspace (4 B elems, ~21 MB)
    int* u = (int*)d_ws;
    size_t o = 0;
    __half2* h2     = (__half2*)(u + o); o += (size_t)(N + 1) * 16;   // +sentinel row
    float*   asrc   = (float*)(u + o);   o += N + 1;                  // +sentinel
    float*   adst   = (float*)(u + o);   o += N;
    int*     cursor = u + o;             o += NBMAX;
    int*     recs   = u + o;             o += (size_t)NBMAX * CAP;    // fixed-CAP regions

    const int PB = (N + 63) / 64;                // MFMA proj blocks (64 nodes/block)

    k_proj<<<PB + 1, 256, 0, stream>>>(x, W, att_src, att_dst, h2, asrc, adst,
                                       cursor, N, NB, PB);
    k_bpart<<<NBLKA, 512, 0, stream>>>(src, dst, cursor, recs, NB, E, epb);
    k_pg<<<NB, 512, 0, stream>>>(recs, cursor, asrc, adst, h2, bias, out, NB, E, N);
}